// Round 2
// baseline (480.256 us; speedup 1.0000x reference)
//
#include <hip/hip_runtime.h>
#include <math.h>

// OnlineLabelSmoothing: B=16384 rows, C=4096 classes, f32.
// out = [loss(1), update(C*C), idx_count(C)] f32.

constexpr int THREADS = 256;
constexpr int WAVE    = 64;
constexpr int NWAVES  = THREADS / WAVE;   // 4
constexpr int CC      = 4096;             // classes (fixed for this problem)
constexpr int PER     = CC / (THREADS * 4); // float4 iters per thread = 4
constexpr float ALPHA_V = 0.5f;

__device__ inline void amax2(float v, int i, float& bv, int& bidx) {
  // first-occurrence argmax: prefer smaller index on exact tie
  if (v > bv || (v == bv && i < bidx)) { bv = v; bidx = i; }
}

__device__ inline void block_argmax(float lv, int li, float* s_v, int* s_i,
                                    float& out_v, int& out_i) {
  #pragma unroll
  for (int o = 1; o < WAVE; o <<= 1) {
    float ov = __shfl_xor(lv, o, WAVE);
    int   oi = __shfl_xor(li, o, WAVE);
    amax2(ov, oi, lv, li);
  }
  const int wid  = threadIdx.x >> 6;
  const int lane = threadIdx.x & 63;
  if (lane == 0) { s_v[wid] = lv; s_i[wid] = li; }
  __syncthreads();
  float bv = s_v[0]; int bidx = s_i[0];
  #pragma unroll
  for (int w = 1; w < NWAVES; ++w) amax2(s_v[w], s_i[w], bv, bidx);
  __syncthreads();  // safe to reuse s_v/s_i after return
  out_v = bv; out_i = bidx;
}

__device__ inline float block_sum(float v, float* s_v) {
  #pragma unroll
  for (int o = 1; o < WAVE; o <<= 1) v += __shfl_xor(v, o, WAVE);
  const int wid  = threadIdx.x >> 6;
  const int lane = threadIdx.x & 63;
  if (lane == 0) s_v[wid] = v;
  __syncthreads();
  float r = 0.f;
  #pragma unroll
  for (int w = 0; w < NWAVES; ++w) r += s_v[w];
  __syncthreads();
  return r;
}

// ---- supervise transpose: supT[y][c] = sup[c][y] ----
__global__ void ols_transpose(const float* __restrict__ in,
                              float* __restrict__ out, int C) {
  __shared__ float tile[32][33];
  const int bx = blockIdx.x * 32, by = blockIdx.y * 32;
  const int tx = threadIdx.x, ty = threadIdx.y;  // (32, 8)
  #pragma unroll
  for (int j = 0; j < 32; j += 8)
    tile[ty + j][tx] = in[(size_t)(by + ty + j) * C + bx + tx];
  __syncthreads();
  #pragma unroll
  for (int j = 0; j < 32; j += 8)
    out[(size_t)(bx + ty + j) * C + by + tx] = tile[tx][ty + j];
}

// ---- main: one block per row ----
__global__ __launch_bounds__(THREADS)
void ols_main(const float* __restrict__ y_h, const float* __restrict__ y,
              const float* __restrict__ sup, int sup_is_T,
              float* __restrict__ upd, float* __restrict__ cnt,
              double* __restrict__ acc) {
  const int b = blockIdx.x;
  const int t = threadIdx.x;
  __shared__ float s_v[NWAVES];
  __shared__ int   s_i[NWAVES];

  const size_t roff = (size_t)b * CC;

  // ---- argmax over y row -> hard label ----
  float lv = -INFINITY; int li = 0x7fffffff;
  {
    const float4* y4 = reinterpret_cast<const float4*>(y + roff);
    #pragma unroll
    for (int k = 0; k < PER; ++k) {
      const int i4 = k * THREADS + t;
      const float4 v = y4[i4];
      const int base = i4 * 4;
      amax2(v.x, base + 0, lv, li);
      amax2(v.y, base + 1, lv, li);
      amax2(v.z, base + 2, lv, li);
      amax2(v.w, base + 3, lv, li);
    }
  }
  float yl_v; int y_label;
  block_argmax(lv, li, s_v, s_i, yl_v, y_label);

  // ---- load y_h row to regs + argmax (pred) / max (m) ----
  float4 r[PER];
  lv = -INFINITY; li = 0x7fffffff;
  {
    const float4* x4 = reinterpret_cast<const float4*>(y_h + roff);
    #pragma unroll
    for (int k = 0; k < PER; ++k) {
      const int i4 = k * THREADS + t;
      r[k] = x4[i4];
      const int base = i4 * 4;
      amax2(r[k].x, base + 0, lv, li);
      amax2(r[k].y, base + 1, lv, li);
      amax2(r[k].z, base + 2, lv, li);
      amax2(r[k].w, base + 3, lv, li);
    }
  }
  float m; int pred;
  block_argmax(lv, li, s_v, s_i, m, pred);

  // ---- sum exp(x - m) ----
  float se = 0.f;
  #pragma unroll
  for (int k = 0; k < PER; ++k) {
    se += expf(r[k].x - m) + expf(r[k].y - m)
        + expf(r[k].z - m) + expf(r[k].w - m);
  }
  const float Z   = block_sum(se, s_v);
  const float lZ  = logf(Z);
  const float mlz = m + lZ;   // -log_p[c] = mlz - x[c]

  // ---- soft dot (supervise column y_label) + hard term ----
  float sacc = 0.f, hacc = 0.f;
  const float* supTrow = sup + (size_t)y_label * CC;  // valid if sup_is_T
  #pragma unroll
  for (int k = 0; k < PER; ++k) {
    const int i4 = k * THREADS + t;
    const int base = i4 * 4;
    float4 w;
    if (sup_is_T) {
      w = reinterpret_cast<const float4*>(supTrow)[i4];
    } else {
      w.x = sup[(size_t)(base + 0) * CC + y_label];
      w.y = sup[(size_t)(base + 1) * CC + y_label];
      w.z = sup[(size_t)(base + 2) * CC + y_label];
      w.w = sup[(size_t)(base + 3) * CC + y_label];
    }
    const float n0 = mlz - r[k].x, n1 = mlz - r[k].y;
    const float n2 = mlz - r[k].z, n3 = mlz - r[k].w;
    sacc += w.x * n0 + w.y * n1 + w.z * n2 + w.w * n3;
    if (base + 0 == y_label) hacc += n0;
    if (base + 1 == y_label) hacc += n1;
    if (base + 2 == y_label) hacc += n2;
    if (base + 3 == y_label) hacc += n3;
  }
  const float soft = block_sum(sacc, s_v);
  const float hard = block_sum(hacc, s_v);

  // ---- scatter-add probs into update column `pred` (rare: pred==label) ----
  if (pred == y_label) {
    const float invZ = 1.0f / Z;
    #pragma unroll
    for (int k = 0; k < PER; ++k) {
      const int base = (k * THREADS + t) * 4;
      atomicAdd(&upd[(size_t)(base + 0) * CC + pred], expf(r[k].x - m) * invZ);
      atomicAdd(&upd[(size_t)(base + 1) * CC + pred], expf(r[k].y - m) * invZ);
      atomicAdd(&upd[(size_t)(base + 2) * CC + pred], expf(r[k].z - m) * invZ);
      atomicAdd(&upd[(size_t)(base + 3) * CC + pred], expf(r[k].w - m) * invZ);
    }
    if (t == 0) atomicAdd(&cnt[pred], 1.0f);
  }

  if (t == 0) {
    atomicAdd(&acc[0], (double)hard);
    atomicAdd(&acc[1], (double)soft);
  }
}

__global__ void ols_finalize(const double* __restrict__ acc,
                             float* __restrict__ out, double invB) {
  out[0] = (float)(((double)ALPHA_V * acc[0] +
                    (1.0 - (double)ALPHA_V) * acc[1]) * invB);
}

extern "C" void kernel_launch(void* const* d_in, const int* in_sizes, int n_in,
                              void* d_out, int out_size, void* d_ws, size_t ws_size,
                              hipStream_t stream) {
  const float* y_h = (const float*)d_in[0];
  const float* y   = (const float*)d_in[1];
  const float* sup = (const float*)d_in[2];
  const int C = CC;                       // 4096 (supervise is C*C)
  const int B = in_sizes[0] / C;          // 16384

  float* out        = (float*)d_out;
  float* out_update = out + 1;
  float* out_count  = out + 1 + (size_t)C * C;

  double* acc = (double*)d_ws;
  const size_t supT_off = 256;
  float* supT = (float*)((char*)d_ws + supT_off);
  const bool useT = ws_size >= supT_off + (size_t)C * C * sizeof(float);

  // zero outputs (update/idx_count accumulated via atomics) + loss accumulators
  hipMemsetAsync(d_out, 0, (size_t)out_size * sizeof(float), stream);
  hipMemsetAsync(d_ws, 0, 256, stream);

  if (useT) {
    dim3 g(C / 32, C / 32), bl(32, 8);
    ols_transpose<<<g, bl, 0, stream>>>(sup, supT, C);
  }

  ols_main<<<B, THREADS, 0, stream>>>(y_h, y, useT ? supT : sup, useT ? 1 : 0,
                                      out_update, out_count, acc);

  ols_finalize<<<1, 1, 0, stream>>>(acc, out, 1.0 / (double)B);
}

// Round 3
// 382.101 us; speedup vs baseline: 1.2569x; 1.2569x over previous
//
#include <hip/hip_runtime.h>
#include <math.h>

// OnlineLabelSmoothing: B=16384 rows, C=4096 classes, f32.
// out = [loss(1), update(C*C), idx_count(C)] f32.
// Round 3: wave-per-row (zero barriers, zero LDS in main), bulk register
// loads for MLP, transpose kernel fused with update-zeroing, spread atomics.

constexpr int CC   = 4096;
constexpr int WAVE = 64;
constexpr int RPB  = 4;              // rows (waves) per block
constexpr int TPB  = WAVE * RPB;     // 256
constexpr int K16  = CC / (WAVE * 4);// 16 float4 per lane per row
constexpr float ALPHA_V = 0.5f;
constexpr int ACC_SLOTS = 64;        // loss accumulator spread (x2 doubles)

__device__ inline void amax2(float v, int i, float& bv, int& bi) {
  // first-occurrence argmax: prefer smaller index on exact tie
  if (v > bv || (v == bv && i < bi)) { bv = v; bi = i; }
}

__device__ inline void wave_argmax(float& lv, int& li) {
  #pragma unroll
  for (int o = 1; o < WAVE; o <<= 1) {
    float ov = __shfl_xor(lv, o, WAVE);
    int   oi = __shfl_xor(li, o, WAVE);
    amax2(ov, oi, lv, li);
  }
}

__device__ inline float wave_sum(float v) {
  #pragma unroll
  for (int o = 1; o < WAVE; o <<= 1) v += __shfl_xor(v, o, WAVE);
  return v;
}

// ---- supervise transpose fused with update zeroing (same extent) ----
__global__ void ols_transpose(const float* __restrict__ in,
                              float* __restrict__ supT,
                              float* __restrict__ upd, int C) {
  __shared__ float tile[32][33];
  const int bx = blockIdx.x * 32, by = blockIdx.y * 32;
  const int tx = threadIdx.x, ty = threadIdx.y;  // (32, 8)
  #pragma unroll
  for (int j = 0; j < 32; j += 8)
    tile[ty + j][tx] = in[(size_t)(by + ty + j) * C + bx + tx];
  __syncthreads();
  #pragma unroll
  for (int j = 0; j < 32; j += 8) {
    const size_t o = (size_t)(bx + ty + j) * C + by + tx;
    supT[o] = tile[tx][ty + j];
    upd[o]  = 0.0f;
  }
}

// ---- zero loss scalar, idx_count, loss accumulators ----
__global__ void ols_zero_small(float* __restrict__ out0,
                               float* __restrict__ cnt,
                               double* __restrict__ acc, int C) {
  const int t = blockIdx.x * blockDim.x + threadIdx.x;
  if (t == 0) out0[0] = 0.0f;
  for (int i = t; i < C; i += blockDim.x * gridDim.x) cnt[i] = 0.0f;
  if (t < ACC_SLOTS * 2) acc[t] = 0.0;
}

// ---- main: one wave per row, no barriers ----
__global__ __launch_bounds__(TPB)
void ols_main(const float* __restrict__ y_h, const float* __restrict__ y,
              const float* __restrict__ sup, int sup_is_T,
              float* __restrict__ upd, float* __restrict__ cnt,
              double* __restrict__ acc) {
  const int wv   = threadIdx.x >> 6;
  const int lane = threadIdx.x & 63;
  const int b    = blockIdx.x * RPB + wv;
  const size_t roff = (size_t)b * CC;

  const float4* x4 = reinterpret_cast<const float4*>(y_h + roff);
  const float4* y4 = reinterpret_cast<const float4*>(y + roff);

  // bulk-load y_h row into registers (overlaps the y-argmax stream below)
  float4 rx[K16];
  #pragma unroll
  for (int k = 0; k < K16; ++k) rx[k] = x4[k * WAVE + lane];

  // ---- streaming argmax over y -> hard label ----
  float lv = -INFINITY; int li = 0x7fffffff;
  #pragma unroll
  for (int k = 0; k < K16; ++k) {
    const float4 v = y4[k * WAVE + lane];
    const int base = (k * WAVE + lane) * 4;
    amax2(v.x, base + 0, lv, li);
    amax2(v.y, base + 1, lv, li);
    amax2(v.z, base + 2, lv, li);
    amax2(v.w, base + 3, lv, li);
  }
  wave_argmax(lv, li);
  const int y_label = li;

  // ---- y_h argmax (pred) and row max (m) ----
  lv = -INFINITY; li = 0x7fffffff;
  #pragma unroll
  for (int k = 0; k < K16; ++k) {
    const int base = (k * WAVE + lane) * 4;
    amax2(rx[k].x, base + 0, lv, li);
    amax2(rx[k].y, base + 1, lv, li);
    amax2(rx[k].z, base + 2, lv, li);
    amax2(rx[k].w, base + 3, lv, li);
  }
  wave_argmax(lv, li);
  const float m = lv;
  const int pred = li;

  // ---- sum exp(x - m) ----
  float se = 0.f;
  #pragma unroll
  for (int k = 0; k < K16; ++k) {
    se += __expf(rx[k].x - m) + __expf(rx[k].y - m)
        + __expf(rx[k].z - m) + __expf(rx[k].w - m);
  }
  const float Z   = wave_sum(se);
  const float mlz = m + __logf(Z);  // -log_p[c] = mlz - x[c]

  // ---- soft dot (supervise column y_label) + hard term ----
  float sacc = 0.f, hacc = 0.f;
  if (sup_is_T) {
    const float4* w4 = reinterpret_cast<const float4*>(sup + (size_t)y_label * CC);
    #pragma unroll
    for (int k = 0; k < K16; ++k) {
      const float4 w = w4[k * WAVE + lane];
      const int base = (k * WAVE + lane) * 4;
      const float n0 = mlz - rx[k].x, n1 = mlz - rx[k].y;
      const float n2 = mlz - rx[k].z, n3 = mlz - rx[k].w;
      sacc += w.x * n0 + w.y * n1 + w.z * n2 + w.w * n3;
      if (base + 0 == y_label) hacc += n0;
      if (base + 1 == y_label) hacc += n1;
      if (base + 2 == y_label) hacc += n2;
      if (base + 3 == y_label) hacc += n3;
    }
  } else {
    #pragma unroll
    for (int k = 0; k < K16; ++k) {
      const int base = (k * WAVE + lane) * 4;
      const float n0 = mlz - rx[k].x, n1 = mlz - rx[k].y;
      const float n2 = mlz - rx[k].z, n3 = mlz - rx[k].w;
      sacc += sup[(size_t)(base + 0) * CC + y_label] * n0
            + sup[(size_t)(base + 1) * CC + y_label] * n1
            + sup[(size_t)(base + 2) * CC + y_label] * n2
            + sup[(size_t)(base + 3) * CC + y_label] * n3;
      if (base + 0 == y_label) hacc += n0;
      if (base + 1 == y_label) hacc += n1;
      if (base + 2 == y_label) hacc += n2;
      if (base + 3 == y_label) hacc += n3;
    }
  }
  const float soft = wave_sum(sacc);
  const float hard = wave_sum(hacc);

  // ---- scatter-add probs into update column `pred` (rare: pred==label) ----
  if (pred == y_label) {
    const float invZ = 1.0f / Z;
    #pragma unroll
    for (int k = 0; k < K16; ++k) {
      const int base = (k * WAVE + lane) * 4;
      atomicAdd(&upd[(size_t)(base + 0) * CC + pred], __expf(rx[k].x - m) * invZ);
      atomicAdd(&upd[(size_t)(base + 1) * CC + pred], __expf(rx[k].y - m) * invZ);
      atomicAdd(&upd[(size_t)(base + 2) * CC + pred], __expf(rx[k].z - m) * invZ);
      atomicAdd(&upd[(size_t)(base + 3) * CC + pred], __expf(rx[k].w - m) * invZ);
    }
    if (lane == 0) atomicAdd(&cnt[pred], 1.0f);
  }

  if (lane == 0) {
    const int slot = (b & (ACC_SLOTS - 1)) * 2;
    atomicAdd(&acc[slot + 0], (double)hard);
    atomicAdd(&acc[slot + 1], (double)soft);
  }
}

__global__ void ols_finalize(const double* __restrict__ acc,
                             float* __restrict__ out, double invB) {
  double h = 0.0, s = 0.0;
  for (int i = 0; i < ACC_SLOTS; ++i) { h += acc[i * 2]; s += acc[i * 2 + 1]; }
  out[0] = (float)(((double)ALPHA_V * h + (1.0 - (double)ALPHA_V) * s) * invB);
}

extern "C" void kernel_launch(void* const* d_in, const int* in_sizes, int n_in,
                              void* d_out, int out_size, void* d_ws, size_t ws_size,
                              hipStream_t stream) {
  const float* y_h = (const float*)d_in[0];
  const float* y   = (const float*)d_in[1];
  const float* sup = (const float*)d_in[2];
  const int C = CC;                       // 4096 (supervise is C*C)
  const int B = in_sizes[0] / C;          // 16384

  float* out        = (float*)d_out;
  float* out_update = out + 1;
  float* out_count  = out + 1 + (size_t)C * C;

  double* acc = (double*)d_ws;
  const size_t supT_off = 4096;
  float* supT = (float*)((char*)d_ws + supT_off);
  const bool useT = ws_size >= supT_off + (size_t)C * C * sizeof(float);

  ols_zero_small<<<16, 256, 0, stream>>>(out, out_count, acc, C);

  if (useT) {
    dim3 g(C / 32, C / 32), bl(32, 8);
    ols_transpose<<<g, bl, 0, stream>>>(sup, supT, out_update, C);
  } else {
    hipMemsetAsync(out_update, 0, (size_t)C * C * sizeof(float), stream);
  }

  ols_main<<<B / RPB, TPB, 0, stream>>>(y_h, y, useT ? supT : sup, useT ? 1 : 0,
                                        out_update, out_count, acc);

  ols_finalize<<<1, 1, 0, stream>>>(acc, out, 1.0 / (double)B);
}

// Round 4
// 241.616 us; speedup vs baseline: 1.9877x; 1.5814x over previous
//
#include <hip/hip_runtime.h>
#include <math.h>

// OnlineLabelSmoothing: B=16384 rows, C=4096 classes, f32.
// out = [loss(1), update(C*C), idx_count(C)] f32.
// Round 4: wave-per-row with BULK register loads for both rows (32
// independent float4 loads issued back-to-back -> 1 HBM latency round,
// not 48), supT gather issued right after y-argmax so its latency hides
// under the y_h argmax/sumexp register compute.

constexpr int CC   = 4096;
constexpr int WAVE = 64;
constexpr int RPB  = 4;              // rows (waves) per block
constexpr int TPB  = WAVE * RPB;     // 256
constexpr int K16  = CC / (WAVE * 4);// 16 float4 per lane per row
constexpr float ALPHA_V = 0.5f;
constexpr int ACC_SLOTS = 64;        // loss accumulator spread (x2 doubles)

__device__ inline void amax2(float v, int i, float& bv, int& bi) {
  // first-occurrence argmax: prefer smaller index on exact tie
  if (v > bv || (v == bv && i < bi)) { bv = v; bi = i; }
}

__device__ inline void wave_argmax(float& lv, int& li) {
  #pragma unroll
  for (int o = 1; o < WAVE; o <<= 1) {
    float ov = __shfl_xor(lv, o, WAVE);
    int   oi = __shfl_xor(li, o, WAVE);
    amax2(ov, oi, lv, li);
  }
}

__device__ inline float wave_sum(float v) {
  #pragma unroll
  for (int o = 1; o < WAVE; o <<= 1) v += __shfl_xor(v, o, WAVE);
  return v;
}

// ---- supervise transpose fused with update zeroing (same extent) ----
__global__ void ols_transpose(const float* __restrict__ in,
                              float* __restrict__ supT,
                              float* __restrict__ upd, int C) {
  __shared__ float tile[32][33];
  const int bx = blockIdx.x * 32, by = blockIdx.y * 32;
  const int tx = threadIdx.x, ty = threadIdx.y;  // (32, 8)
  #pragma unroll
  for (int j = 0; j < 32; j += 8)
    tile[ty + j][tx] = in[(size_t)(by + ty + j) * C + bx + tx];
  __syncthreads();
  #pragma unroll
  for (int j = 0; j < 32; j += 8) {
    const size_t o = (size_t)(bx + ty + j) * C + by + tx;
    supT[o] = tile[tx][ty + j];
    upd[o]  = 0.0f;
  }
}

// ---- zero loss scalar, idx_count, loss accumulators ----
__global__ void ols_zero_small(float* __restrict__ out0,
                               float* __restrict__ cnt,
                               double* __restrict__ acc, int C) {
  const int t = blockIdx.x * blockDim.x + threadIdx.x;
  if (t == 0) out0[0] = 0.0f;
  for (int i = t; i < C; i += blockDim.x * gridDim.x) cnt[i] = 0.0f;
  if (t < ACC_SLOTS * 2) acc[t] = 0.0;
}

// ---- main: one wave per row, no barriers, bulk loads ----
__global__ __launch_bounds__(TPB)
void ols_main(const float* __restrict__ y_h, const float* __restrict__ y,
              const float* __restrict__ supT,
              float* __restrict__ upd, float* __restrict__ cnt,
              double* __restrict__ acc) {
  const int wv   = threadIdx.x >> 6;
  const int lane = threadIdx.x & 63;
  const int b    = blockIdx.x * RPB + wv;
  const size_t roff = (size_t)b * CC;

  const float4* x4 = reinterpret_cast<const float4*>(y_h + roff);
  const float4* y4 = reinterpret_cast<const float4*>(y + roff);

  // ---- bulk-issue BOTH row streams (32 independent loads) ----
  float4 ry[K16];
  #pragma unroll
  for (int k = 0; k < K16; ++k) ry[k] = y4[k * WAVE + lane];
  float4 rx[K16];
  #pragma unroll
  for (int k = 0; k < K16; ++k) rx[k] = x4[k * WAVE + lane];

  // ---- y argmax (register-only) -> hard label ----
  float lv = -INFINITY; int li = 0x7fffffff;
  #pragma unroll
  for (int k = 0; k < K16; ++k) {
    const int base = (k * WAVE + lane) * 4;
    amax2(ry[k].x, base + 0, lv, li);
    amax2(ry[k].y, base + 1, lv, li);
    amax2(ry[k].z, base + 2, lv, li);
    amax2(ry[k].w, base + 3, lv, li);
  }
  wave_argmax(lv, li);
  const int y_label = li;   // ry dead from here -> regs reusable for rw

  // ---- issue supT row gather NOW; latency hides under y_h compute ----
  const float4* w4 = reinterpret_cast<const float4*>(supT + (size_t)y_label * CC);
  float4 rw[K16];
  #pragma unroll
  for (int k = 0; k < K16; ++k) rw[k] = w4[k * WAVE + lane];

  // ---- y_h argmax (pred) and row max (m), register-only ----
  lv = -INFINITY; li = 0x7fffffff;
  #pragma unroll
  for (int k = 0; k < K16; ++k) {
    const int base = (k * WAVE + lane) * 4;
    amax2(rx[k].x, base + 0, lv, li);
    amax2(rx[k].y, base + 1, lv, li);
    amax2(rx[k].z, base + 2, lv, li);
    amax2(rx[k].w, base + 3, lv, li);
  }
  wave_argmax(lv, li);
  const float m = lv;
  const int pred = li;

  // ---- sum exp(x - m), register-only ----
  float se = 0.f;
  #pragma unroll
  for (int k = 0; k < K16; ++k) {
    se += __expf(rx[k].x - m) + __expf(rx[k].y - m)
        + __expf(rx[k].z - m) + __expf(rx[k].w - m);
  }
  const float Z   = wave_sum(se);
  const float mlz = m + __logf(Z);  // -log_p[c] = mlz - x[c]

  // ---- soft dot (first use of rw) + hard term ----
  float sacc = 0.f, hacc = 0.f;
  #pragma unroll
  for (int k = 0; k < K16; ++k) {
    const int base = (k * WAVE + lane) * 4;
    const float n0 = mlz - rx[k].x, n1 = mlz - rx[k].y;
    const float n2 = mlz - rx[k].z, n3 = mlz - rx[k].w;
    sacc += rw[k].x * n0 + rw[k].y * n1 + rw[k].z * n2 + rw[k].w * n3;
    if (base + 0 == y_label) hacc += n0;
    if (base + 1 == y_label) hacc += n1;
    if (base + 2 == y_label) hacc += n2;
    if (base + 3 == y_label) hacc += n3;
  }
  const float soft = wave_sum(sacc);
  const float hard = wave_sum(hacc);

  // ---- scatter-add probs into update column `pred` (rare: pred==label) ----
  if (pred == y_label) {
    const float invZ = 1.0f / Z;
    #pragma unroll
    for (int k = 0; k < K16; ++k) {
      const int base = (k * WAVE + lane) * 4;
      atomicAdd(&upd[(size_t)(base + 0) * CC + pred], __expf(rx[k].x - m) * invZ);
      atomicAdd(&upd[(size_t)(base + 1) * CC + pred], __expf(rx[k].y - m) * invZ);
      atomicAdd(&upd[(size_t)(base + 2) * CC + pred], __expf(rx[k].z - m) * invZ);
      atomicAdd(&upd[(size_t)(base + 3) * CC + pred], __expf(rx[k].w - m) * invZ);
    }
    if (lane == 0) atomicAdd(&cnt[pred], 1.0f);
  }

  if (lane == 0) {
    const int slot = (b & (ACC_SLOTS - 1)) * 2;
    atomicAdd(&acc[slot + 0], (double)hard);
    atomicAdd(&acc[slot + 1], (double)soft);
  }
}

__global__ void ols_finalize(const double* __restrict__ acc,
                             float* __restrict__ out, double invB) {
  double h = 0.0, s = 0.0;
  for (int i = 0; i < ACC_SLOTS; ++i) { h += acc[i * 2]; s += acc[i * 2 + 1]; }
  out[0] = (float)(((double)ALPHA_V * h + (1.0 - (double)ALPHA_V) * s) * invB);
}

extern "C" void kernel_launch(void* const* d_in, const int* in_sizes, int n_in,
                              void* d_out, int out_size, void* d_ws, size_t ws_size,
                              hipStream_t stream) {
  const float* y_h = (const float*)d_in[0];
  const float* y   = (const float*)d_in[1];
  const float* sup = (const float*)d_in[2];
  const int C = CC;                       // 4096 (supervise is C*C)
  const int B = in_sizes[0] / C;          // 16384

  float* out        = (float*)d_out;
  float* out_update = out + 1;
  float* out_count  = out + 1 + (size_t)C * C;

  double* acc = (double*)d_ws;
  const size_t supT_off = 4096;
  float* supT = (float*)((char*)d_ws + supT_off);

  ols_zero_small<<<16, 256, 0, stream>>>(out, out_count, acc, C);

  {
    dim3 g(C / 32, C / 32), bl(32, 8);
    ols_transpose<<<g, bl, 0, stream>>>(sup, supT, out_update, C);
  }

  ols_main<<<B / RPB, TPB, 0, stream>>>(y_h, y, supT,
                                        out_update, out_count, acc);

  ols_finalize<<<1, 1, 0, stream>>>(acc, out, 1.0 / (double)B);
}